// Round 4
// baseline (452.216 us; speedup 1.0000x reference)
//
#include <hip/hip_runtime.h>
#include <hip/hip_bf16.h>

#define IN_DIM 128
#define HC 128   // H*C
#define NH 4     // heads
#define CH 32    // channels per head
#define EDGE_DIM 32

// ---------------------------------------------------------------------------
// pack two f32 -> bf16x2 (round-to-nearest-even), result uint
// ---------------------------------------------------------------------------
__device__ __forceinline__ unsigned pack_bf16(float a, float b) {
    unsigned ua = __float_as_uint(a), ub = __float_as_uint(b);
    ua += 0x7fffu + ((ua >> 16) & 1u);
    ub += 0x7fffu + ((ub >> 16) & 1u);
    return (ua >> 16) | (ub & 0xffff0000u);
}

// ---------------------------------------------------------------------------
// K0: v_edge[h][k] = sum_c W_edge[k, h*32+c] * att_edge[h, c]   (4x32 floats)
// ---------------------------------------------------------------------------
__global__ void k_vedge(const float* __restrict__ W_edge,
                        const float* __restrict__ att_edge,
                        float* __restrict__ v_edge) {
    int t = threadIdx.x;           // 128 threads
    int h = t >> 5, k = t & 31;
    float s = 0.f;
    #pragma unroll
    for (int c = 0; c < CH; ++c)
        s += W_edge[k * HC + h * CH + c] * att_edge[h * CH + c];
    v_edge[h * EDGE_DIM + k] = s;
}

// ---------------------------------------------------------------------------
// K1: x = point_attr @ W  [N,128] stored as bf16; fused a_src/a_dst epilogue.
// ---------------------------------------------------------------------------
__global__ __launch_bounds__(256) void k_gemm_x(
    const float* __restrict__ A, const float* __restrict__ Wg,
    const float* __restrict__ att_src, const float* __restrict__ att_dst,
    unsigned* __restrict__ xb, float* __restrict__ a_src, float* __restrict__ a_dst,
    int N)
{
    __shared__ float4 Wl[128 * 32];   // 64 KB: W[k][c4]
    __shared__ float4 Rl[128 * 32];   // 64 KB: A rows, k4-index XOR row&31

    int t = threadIdx.x;
    int node0 = blockIdx.x * 128;

    const float4* Wg4 = (const float4*)Wg;
    #pragma unroll
    for (int i = 0; i < 16; ++i) {
        int id = i * 256 + t;
        Wl[id] = Wg4[id];
    }
    const float4* A4 = (const float4*)A;
    #pragma unroll
    for (int i = 0; i < 16; ++i) {
        int id = i * 256 + t;
        int row = id >> 5, c = id & 31;
        float4 v = {0.f, 0.f, 0.f, 0.f};
        if (node0 + row < N) v = A4[(size_t)(node0 + row) * 32 + c];
        Rl[row * 32 + (c ^ (row & 31))] = v;
    }
    __syncthreads();

    int tr = t >> 4, tc = t & 15;
    float4 acc0[8], acc1[8];
    #pragma unroll
    for (int i = 0; i < 8; ++i) {
        acc0[i] = {0.f, 0.f, 0.f, 0.f};
        acc1[i] = {0.f, 0.f, 0.f, 0.f};
    }

    for (int k4 = 0; k4 < 32; ++k4) {
        float4 rv[8];
        #pragma unroll
        for (int i = 0; i < 8; ++i) {
            int r = tr + 16 * i;
            rv[i] = Rl[r * 32 + (k4 ^ (r & 31))];
        }
        #pragma unroll
        for (int kk = 0; kk < 4; ++kk) {
            int k = k4 * 4 + kk;
            float4 w0 = Wl[k * 32 + tc];
            float4 w1 = Wl[k * 32 + 16 + tc];
            #pragma unroll
            for (int i = 0; i < 8; ++i) {
                float a = (kk == 0) ? rv[i].x : (kk == 1) ? rv[i].y
                        : (kk == 2) ? rv[i].z : rv[i].w;
                acc0[i].x += a * w0.x; acc0[i].y += a * w0.y;
                acc0[i].z += a * w0.z; acc0[i].w += a * w0.w;
                acc1[i].x += a * w1.x; acc1[i].y += a * w1.y;
                acc1[i].z += a * w1.z; acc1[i].w += a * w1.w;
            }
        }
    }

    int h0 = tc >> 3;
    int co = (tc & 7) * 4;
    float4 as0 = *(const float4*)&att_src[h0 * CH + co];
    float4 as1 = *(const float4*)&att_src[(h0 + 2) * CH + co];
    float4 ad0 = *(const float4*)&att_dst[h0 * CH + co];
    float4 ad1 = *(const float4*)&att_dst[(h0 + 2) * CH + co];
    uint2* x2 = (uint2*)xb;

    #pragma unroll
    for (int i = 0; i < 8; ++i) {
        int r = tr + 16 * i;
        int node = node0 + r;
        bool ok = node < N;
        if (ok) {
            uint2 p0 = {pack_bf16(acc0[i].x, acc0[i].y), pack_bf16(acc0[i].z, acc0[i].w)};
            uint2 p1 = {pack_bf16(acc1[i].x, acc1[i].y), pack_bf16(acc1[i].z, acc1[i].w)};
            x2[(size_t)node * 32 + tc]      = p0;
            x2[(size_t)node * 32 + 16 + tc] = p1;
        }
        float ps0 = acc0[i].x * as0.x + acc0[i].y * as0.y + acc0[i].z * as0.z + acc0[i].w * as0.w;
        float ps1 = acc1[i].x * as1.x + acc1[i].y * as1.y + acc1[i].z * as1.z + acc1[i].w * as1.w;
        float pd0 = acc0[i].x * ad0.x + acc0[i].y * ad0.y + acc0[i].z * ad0.z + acc0[i].w * ad0.w;
        float pd1 = acc1[i].x * ad1.x + acc1[i].y * ad1.y + acc1[i].z * ad1.z + acc1[i].w * ad1.w;
        #pragma unroll
        for (int m = 1; m <= 4; m <<= 1) {
            ps0 += __shfl_xor(ps0, m); ps1 += __shfl_xor(ps1, m);
            pd0 += __shfl_xor(pd0, m); pd1 += __shfl_xor(pd1, m);
        }
        if (ok && (tc & 7) == 0) {
            a_src[node * 4 + h0]     = ps0;
            a_src[node * 4 + h0 + 2] = ps1;
            a_dst[node * 4 + h0]     = pd0;
            a_dst[node * 4 + h0 + 2] = pd1;
        }
    }
}

// ---------------------------------------------------------------------------
// K2: degree histogram (int atomics only, dst stream)
// ---------------------------------------------------------------------------
__global__ __launch_bounds__(256) void k_degree(const int* __restrict__ ei,
                                                int* __restrict__ degree, int E) {
    int e = blockIdx.x * 256 + threadIdx.x;
    if (e < E) atomicAdd(&degree[ei[E + e]], 1);
}

// ---------------------------------------------------------------------------
// K3a: per-block scan. 1024 thr x 4 elem (int4).
// ---------------------------------------------------------------------------
__global__ __launch_bounds__(1024) void k_scan_blk(
    const int* __restrict__ degree, int* __restrict__ local,
    int* __restrict__ blocksum, int N)
{
    __shared__ int sums[1024];
    int t = threadIdx.x;
    int base = blockIdx.x * 4096 + t * 4;
    int4 d = {0, 0, 0, 0};
    if (base + 3 < N) d = *(const int4*)&degree[base];
    else {
        if (base + 0 < N) d.x = degree[base + 0];
        if (base + 1 < N) d.y = degree[base + 1];
        if (base + 2 < N) d.z = degree[base + 2];
        if (base + 3 < N) d.w = degree[base + 3];
    }
    int s = d.x + d.y + d.z + d.w;
    sums[t] = s;
    __syncthreads();
    #pragma unroll
    for (int dd = 1; dd < 1024; dd <<= 1) {
        int v = (t >= dd) ? sums[t - dd] : 0;
        __syncthreads();
        sums[t] += v;
        __syncthreads();
    }
    int ex = sums[t] - s;
    if (t == 1023) blocksum[blockIdx.x] = sums[1023];
    int4 o;
    o.x = ex;
    o.y = o.x + d.x;
    o.z = o.y + d.y;
    o.w = o.z + d.z;
    if (base + 3 < N) *(int4*)&local[base] = o;
    else {
        if (base + 0 < N) local[base + 0] = o.x;
        if (base + 1 < N) local[base + 1] = o.y;
        if (base + 2 < N) local[base + 2] = o.z;
        if (base + 3 < N) local[base + 3] = o.w;
    }
}

// ---------------------------------------------------------------------------
// K3b: scan block sums in-place -> exclusive block bases; offsets[N] = E.
// ---------------------------------------------------------------------------
__global__ __launch_bounds__(1024) void k_scan_top(
    int* __restrict__ blocksum, int nb, int* __restrict__ offsets, int N)
{
    __shared__ int sums[1024];
    int t = threadIdx.x;
    int v = (t < nb) ? blocksum[t] : 0;
    sums[t] = v;
    __syncthreads();
    #pragma unroll
    for (int d = 1; d < 1024; d <<= 1) {
        int u = (t >= d) ? sums[t - d] : 0;
        __syncthreads();
        sums[t] += u;
        __syncthreads();
    }
    if (t < nb) blocksum[t] = sums[t] - v;
    if (t == nb - 1) offsets[N] = sums[t];
}

// ---------------------------------------------------------------------------
// K3c: add block base; write offsets + cursor.
// ---------------------------------------------------------------------------
__global__ __launch_bounds__(1024) void k_scan_add(
    const int* __restrict__ local, const int* __restrict__ blocksum,
    int* __restrict__ offsets, int* __restrict__ cursor, int N)
{
    int base = blockIdx.x * 4096 + threadIdx.x * 4;
    int bs = blocksum[blockIdx.x];
    if (base + 3 < N) {
        int4 o = *(const int4*)&local[base];
        o.x += bs; o.y += bs; o.z += bs; o.w += bs;
        *(int4*)&offsets[base] = o;
        *(int4*)&cursor[base]  = o;
    } else {
        for (int j = 0; j < 4; ++j)
            if (base + j < N) {
                int o = local[base + j] + bs;
                offsets[base + j] = o;
                cursor[base + j]  = o;
            }
    }
}

// ---------------------------------------------------------------------------
// K4: fused edge stream: full logit -> expa (bf16x4, 8B) + CSR scatter (12B).
// a_src/a_dst gathers are L2-resident (1.6 MB each).
// ---------------------------------------------------------------------------
__global__ __launch_bounds__(256) void k_scatter(
    const float* __restrict__ edge_attr, const int* __restrict__ ei,
    const float* __restrict__ v_edge, const float* __restrict__ a_src,
    const float* __restrict__ a_dst, int* __restrict__ cursor,
    int* __restrict__ csr_src, uint2* __restrict__ csr_expa, int E)
{
    __shared__ float vl[HC];
    int t = threadIdx.x;
    if (t < HC) vl[t] = v_edge[t];
    __syncthreads();

    int e = blockIdx.x * 256 + t;
    if (e >= E) return;

    const float4* ea4 = (const float4*)edge_attr + (size_t)e * 8;
    float ae[4] = {0.f, 0.f, 0.f, 0.f};
    #pragma unroll
    for (int j = 0; j < 8; ++j) {
        float4 v = ea4[j];
        #pragma unroll
        for (int h = 0; h < 4; ++h) {
            const float* vh = &vl[h * 32 + j * 4];
            ae[h] += v.x * vh[0] + v.y * vh[1] + v.z * vh[2] + v.w * vh[3];
        }
    }
    int src = ei[e], dst = ei[E + e];
    float4 as = ((const float4*)a_src)[src];
    float4 ad = ((const float4*)a_dst)[dst];
    float al[4];
    al[0] = as.x + ad.x + ae[0];
    al[1] = as.y + ad.y + ae[1];
    al[2] = as.z + ad.z + ae[2];
    al[3] = as.w + ad.w + ae[3];
    float ex[4];
    #pragma unroll
    for (int h = 0; h < 4; ++h) {
        float a = al[h];
        a = (a < 0.f) ? 0.2f * a : a;
        ex[h] = __expf(a);
    }
    uint2 pk = {pack_bf16(ex[0], ex[1]), pack_bf16(ex[2], ex[3])};
    int pos = atomicAdd(&cursor[dst], 1);
    csr_src[pos] = src;
    csr_expa[pos] = pk;
}

// ---------------------------------------------------------------------------
// K5: fused pull: denom + weighted sum, expa precomputed (bf16x4 broadcast).
// 32 lanes/node (lane -> 4 channels, bf16 x), 4-edge groups, 1-ahead prefetch.
// ---------------------------------------------------------------------------
__global__ __launch_bounds__(256) void k_agg(
    const int* __restrict__ offsets, const int* __restrict__ csr_src,
    const uint2* __restrict__ csr_expa, const unsigned* __restrict__ xb,
    float* __restrict__ out, int N)
{
    int t = threadIdx.x;
    int node = blockIdx.x * 8 + (t >> 5);
    int lane = t & 31;
    if (node >= N) return;
    int st = offsets[node], en = offsets[node + 1];
    int hsel = lane >> 3;
    const uint2* x2 = (const uint2*)xb;
    float4 acc = {0.f, 0.f, 0.f, 0.f};
    float denom = 0.f;

    int s_c[4]; float ex_c[4];

    if (st < en) {
        #pragma unroll
        for (int j = 0; j < 4; ++j) {
            bool v = (st + j) < en;
            int a = v ? (st + j) : 0;
            s_c[j] = csr_src[a];
            uint2 ew = csr_expa[a];
            unsigned w = (hsel & 2) ? ew.y : ew.x;
            float e = __uint_as_float((hsel & 1) ? (w & 0xffff0000u) : (w << 16));
            ex_c[j] = v ? e : 0.f;
        }

        for (int p = st; p < en; p += 4) {
            int pn = p + 4;
            int s_n[4]; float ex_n[4];
            #pragma unroll
            for (int j = 0; j < 4; ++j) {
                bool v = (pn + j) < en;
                int a = v ? (pn + j) : 0;
                s_n[j] = csr_src[a];
                uint2 ew = csr_expa[a];
                unsigned w = (hsel & 2) ? ew.y : ew.x;
                float e = __uint_as_float((hsel & 1) ? (w & 0xffff0000u) : (w << 16));
                ex_n[j] = v ? e : 0.f;
            }

            #pragma unroll
            for (int j = 0; j < 4; ++j) {
                float ex = ex_c[j];
                denom += ex;
                uint2 xv = x2[(size_t)s_c[j] * 32 + lane];
                float x0 = __uint_as_float(xv.x << 16);
                float x1 = __uint_as_float(xv.x & 0xffff0000u);
                float xA = __uint_as_float(xv.y << 16);
                float x3 = __uint_as_float(xv.y & 0xffff0000u);
                acc.x += ex * x0; acc.y += ex * x1;
                acc.z += ex * xA; acc.w += ex * x3;
            }
            #pragma unroll
            for (int j = 0; j < 4; ++j) {
                s_c[j] = s_n[j]; ex_c[j] = ex_n[j];
            }
        }
    }
    float inv = 1.f / (denom + 1e-16f);
    float4 o = {acc.x * inv, acc.y * inv, acc.z * inv, acc.w * inv};
    ((float4*)out)[(size_t)node * 32 + lane] = o;
}

// ---------------------------------------------------------------------------
// K6: +bias, LayerNorm(128), LeakyReLU(0.01). One 64-lane wave per row.
// ---------------------------------------------------------------------------
__global__ __launch_bounds__(256) void k_ln(
    float* __restrict__ out, const float* __restrict__ bias,
    const float* __restrict__ gamma, const float* __restrict__ beta, int N)
{
    int t = threadIdx.x;
    int row = blockIdx.x * 4 + (t >> 6);
    int lane = t & 63;
    if (row >= N) return;
    float2 v = ((const float2*)out)[(size_t)row * 64 + lane];
    int c = lane * 2;
    v.x += bias[c]; v.y += bias[c + 1];
    float s = v.x + v.y;
    #pragma unroll
    for (int m = 1; m < 64; m <<= 1) s += __shfl_xor(s, m);
    float mu = s * (1.0f / 128.0f);
    float dx = v.x - mu, dy = v.y - mu;
    float q = dx * dx + dy * dy;
    #pragma unroll
    for (int m = 1; m < 64; m <<= 1) q += __shfl_xor(q, m);
    float rstd = rsqrtf(q * (1.0f / 128.0f) + 1e-5f);
    float y0 = dx * rstd * gamma[c] + beta[c];
    float y1 = dy * rstd * gamma[c + 1] + beta[c + 1];
    y0 = (y0 < 0.f) ? 0.01f * y0 : y0;
    y1 = (y1 < 0.f) ? 0.01f * y1 : y1;
    float2 r; r.x = y0; r.y = y1;
    ((float2*)out)[(size_t)row * 64 + lane] = r;
}

// ---------------------------------------------------------------------------
extern "C" void kernel_launch(void* const* d_in, const int* in_sizes, int n_in,
                              void* d_out, int out_size, void* d_ws, size_t ws_size,
                              hipStream_t stream) {
    const float* point_attr = (const float*)d_in[0];
    const int*   edge_index = (const int*)d_in[1];
    const float* edge_attr  = (const float*)d_in[2];
    const float* W          = (const float*)d_in[3];
    const float* att_src    = (const float*)d_in[4];
    const float* att_dst    = (const float*)d_in[5];
    const float* W_edge     = (const float*)d_in[6];
    const float* att_edge   = (const float*)d_in[7];
    const float* bias       = (const float*)d_in[8];
    const float* ln_gamma   = (const float*)d_in[9];
    const float* ln_beta    = (const float*)d_in[10];

    int N = in_sizes[0] / IN_DIM;
    int E = in_sizes[2] / EDGE_DIM;
    float* out = (float*)d_out;

    char* ws = (char*)d_ws;
    size_t off = 0;
    auto alloc = [&](size_t bytes) {
        void* p = ws + off;
        off += (bytes + 255) & ~(size_t)255;
        return p;
    };
    unsigned* xb     = (unsigned*)alloc((size_t)N * 128 * 2);   // bf16 x
    float* a_src     = (float*)alloc((size_t)N * 4 * 4);
    float* a_dst     = (float*)alloc((size_t)N * 4 * 4);
    int*   degree    = (int*)alloc((size_t)N * 4);
    int*   offsets   = (int*)alloc((size_t)(N + 1) * 4);
    int*   cursor    = (int*)alloc((size_t)N * 4);
    int*   scanloc   = (int*)alloc((size_t)N * 4);
    int*   blocksum  = (int*)alloc(1024 * 4);
    float* v_edge    = (float*)alloc(128 * 4);
    int*   csr_src   = (int*)alloc((size_t)E * 4);
    uint2* csr_expa  = (uint2*)alloc((size_t)E * 8);

    hipMemsetAsync(degree, 0, (size_t)N * 4, stream);

    int nb = (N + 4095) / 4096;

    k_vedge<<<1, 128, 0, stream>>>(W_edge, att_edge, v_edge);
    k_gemm_x<<<(N + 127) / 128, 256, 0, stream>>>(point_attr, W, att_src, att_dst,
                                                  xb, a_src, a_dst, N);
    k_degree<<<(E + 255) / 256, 256, 0, stream>>>(edge_index, degree, E);
    k_scan_blk<<<nb, 1024, 0, stream>>>(degree, scanloc, blocksum, N);
    k_scan_top<<<1, 1024, 0, stream>>>(blocksum, nb, offsets, N);
    k_scan_add<<<nb, 1024, 0, stream>>>(scanloc, blocksum, offsets, cursor, N);
    k_scatter<<<(E + 255) / 256, 256, 0, stream>>>(edge_attr, edge_index, v_edge,
                                                   a_src, a_dst, cursor,
                                                   csr_src, csr_expa, E);
    k_agg<<<(N + 7) / 8, 256, 0, stream>>>(offsets, csr_src, csr_expa, xb, out, N);
    k_ln<<<(N + 3) / 4, 256, 0, stream>>>(out, bias, ln_gamma, ln_beta, N);
}

// Round 5
// 375.704 us; speedup vs baseline: 1.2036x; 1.2036x over previous
//
#include <hip/hip_runtime.h>
#include <hip/hip_bf16.h>

#define IN_DIM 128
#define HC 128   // H*C
#define NH 4     // heads
#define CH 32    // channels per head
#define EDGE_DIM 32

// ---------------------------------------------------------------------------
// pack two f32 -> bf16x2 (round-to-nearest-even), result uint
// ---------------------------------------------------------------------------
__device__ __forceinline__ unsigned pack_bf16(float a, float b) {
    unsigned ua = __float_as_uint(a), ub = __float_as_uint(b);
    ua += 0x7fffu + ((ua >> 16) & 1u);
    ub += 0x7fffu + ((ub >> 16) & 1u);
    return (ua >> 16) | (ub & 0xffff0000u);
}

// ---------------------------------------------------------------------------
// K0: v_edge[h][k] = sum_c W_edge[k, h*32+c] * att_edge[h, c]   (4x32 floats)
// ---------------------------------------------------------------------------
__global__ void k_vedge(const float* __restrict__ W_edge,
                        const float* __restrict__ att_edge,
                        float* __restrict__ v_edge) {
    int t = threadIdx.x;           // 128 threads
    int h = t >> 5, k = t & 31;
    float s = 0.f;
    #pragma unroll
    for (int c = 0; c < CH; ++c)
        s += W_edge[k * HC + h * CH + c] * att_edge[h * CH + c];
    v_edge[h * EDGE_DIM + k] = s;
}

// ---------------------------------------------------------------------------
// K1: x = point_attr @ W  [N,128] stored as bf16; fused a_src/a_dst epilogue.
// ---------------------------------------------------------------------------
__global__ __launch_bounds__(256) void k_gemm_x(
    const float* __restrict__ A, const float* __restrict__ Wg,
    const float* __restrict__ att_src, const float* __restrict__ att_dst,
    unsigned* __restrict__ xb, float* __restrict__ a_src, float* __restrict__ a_dst,
    int N)
{
    __shared__ float4 Wl[128 * 32];   // 64 KB: W[k][c4]
    __shared__ float4 Rl[128 * 32];   // 64 KB: A rows, k4-index XOR row&31

    int t = threadIdx.x;
    int node0 = blockIdx.x * 128;

    const float4* Wg4 = (const float4*)Wg;
    #pragma unroll
    for (int i = 0; i < 16; ++i) {
        int id = i * 256 + t;
        Wl[id] = Wg4[id];
    }
    const float4* A4 = (const float4*)A;
    #pragma unroll
    for (int i = 0; i < 16; ++i) {
        int id = i * 256 + t;
        int row = id >> 5, c = id & 31;
        float4 v = {0.f, 0.f, 0.f, 0.f};
        if (node0 + row < N) v = A4[(size_t)(node0 + row) * 32 + c];
        Rl[row * 32 + (c ^ (row & 31))] = v;
    }
    __syncthreads();

    int tr = t >> 4, tc = t & 15;
    float4 acc0[8], acc1[8];
    #pragma unroll
    for (int i = 0; i < 8; ++i) {
        acc0[i] = {0.f, 0.f, 0.f, 0.f};
        acc1[i] = {0.f, 0.f, 0.f, 0.f};
    }

    for (int k4 = 0; k4 < 32; ++k4) {
        float4 rv[8];
        #pragma unroll
        for (int i = 0; i < 8; ++i) {
            int r = tr + 16 * i;
            rv[i] = Rl[r * 32 + (k4 ^ (r & 31))];
        }
        #pragma unroll
        for (int kk = 0; kk < 4; ++kk) {
            int k = k4 * 4 + kk;
            float4 w0 = Wl[k * 32 + tc];
            float4 w1 = Wl[k * 32 + 16 + tc];
            #pragma unroll
            for (int i = 0; i < 8; ++i) {
                float a = (kk == 0) ? rv[i].x : (kk == 1) ? rv[i].y
                        : (kk == 2) ? rv[i].z : rv[i].w;
                acc0[i].x += a * w0.x; acc0[i].y += a * w0.y;
                acc0[i].z += a * w0.z; acc0[i].w += a * w0.w;
                acc1[i].x += a * w1.x; acc1[i].y += a * w1.y;
                acc1[i].z += a * w1.z; acc1[i].w += a * w1.w;
            }
        }
    }

    int h0 = tc >> 3;
    int co = (tc & 7) * 4;
    float4 as0 = *(const float4*)&att_src[h0 * CH + co];
    float4 as1 = *(const float4*)&att_src[(h0 + 2) * CH + co];
    float4 ad0 = *(const float4*)&att_dst[h0 * CH + co];
    float4 ad1 = *(const float4*)&att_dst[(h0 + 2) * CH + co];
    uint2* x2 = (uint2*)xb;

    #pragma unroll
    for (int i = 0; i < 8; ++i) {
        int r = tr + 16 * i;
        int node = node0 + r;
        bool ok = node < N;
        if (ok) {
            uint2 p0 = {pack_bf16(acc0[i].x, acc0[i].y), pack_bf16(acc0[i].z, acc0[i].w)};
            uint2 p1 = {pack_bf16(acc1[i].x, acc1[i].y), pack_bf16(acc1[i].z, acc1[i].w)};
            x2[(size_t)node * 32 + tc]      = p0;
            x2[(size_t)node * 32 + 16 + tc] = p1;
        }
        float ps0 = acc0[i].x * as0.x + acc0[i].y * as0.y + acc0[i].z * as0.z + acc0[i].w * as0.w;
        float ps1 = acc1[i].x * as1.x + acc1[i].y * as1.y + acc1[i].z * as1.z + acc1[i].w * as1.w;
        float pd0 = acc0[i].x * ad0.x + acc0[i].y * ad0.y + acc0[i].z * ad0.z + acc0[i].w * ad0.w;
        float pd1 = acc1[i].x * ad1.x + acc1[i].y * ad1.y + acc1[i].z * ad1.z + acc1[i].w * ad1.w;
        #pragma unroll
        for (int m = 1; m <= 4; m <<= 1) {
            ps0 += __shfl_xor(ps0, m); ps1 += __shfl_xor(ps1, m);
            pd0 += __shfl_xor(pd0, m); pd1 += __shfl_xor(pd1, m);
        }
        if (ok && (tc & 7) == 0) {
            a_src[node * 4 + h0]     = ps0;
            a_src[node * 4 + h0 + 2] = ps1;
            a_dst[node * 4 + h0]     = pd0;
            a_dst[node * 4 + h0 + 2] = pd1;
        }
    }
}

// ---------------------------------------------------------------------------
// K2: degree histogram (int atomics only, dst stream)
// ---------------------------------------------------------------------------
__global__ __launch_bounds__(256) void k_degree(const int* __restrict__ ei,
                                                int* __restrict__ degree, int E) {
    int e = blockIdx.x * 256 + threadIdx.x;
    if (e < E) atomicAdd(&degree[ei[E + e]], 1);
}

// ---------------------------------------------------------------------------
// K3a: per-block scan. 1024 thr x 4 elem (int4).
// ---------------------------------------------------------------------------
__global__ __launch_bounds__(1024) void k_scan_blk(
    const int* __restrict__ degree, int* __restrict__ local,
    int* __restrict__ blocksum, int N)
{
    __shared__ int sums[1024];
    int t = threadIdx.x;
    int base = blockIdx.x * 4096 + t * 4;
    int4 d = {0, 0, 0, 0};
    if (base + 3 < N) d = *(const int4*)&degree[base];
    else {
        if (base + 0 < N) d.x = degree[base + 0];
        if (base + 1 < N) d.y = degree[base + 1];
        if (base + 2 < N) d.z = degree[base + 2];
        if (base + 3 < N) d.w = degree[base + 3];
    }
    int s = d.x + d.y + d.z + d.w;
    sums[t] = s;
    __syncthreads();
    #pragma unroll
    for (int dd = 1; dd < 1024; dd <<= 1) {
        int v = (t >= dd) ? sums[t - dd] : 0;
        __syncthreads();
        sums[t] += v;
        __syncthreads();
    }
    int ex = sums[t] - s;
    if (t == 1023) blocksum[blockIdx.x] = sums[1023];
    int4 o;
    o.x = ex;
    o.y = o.x + d.x;
    o.z = o.y + d.y;
    o.w = o.z + d.z;
    if (base + 3 < N) *(int4*)&local[base] = o;
    else {
        if (base + 0 < N) local[base + 0] = o.x;
        if (base + 1 < N) local[base + 1] = o.y;
        if (base + 2 < N) local[base + 2] = o.z;
        if (base + 3 < N) local[base + 3] = o.w;
    }
}

// ---------------------------------------------------------------------------
// K3b: scan block sums in-place -> exclusive block bases; offsets[N] = E.
// ---------------------------------------------------------------------------
__global__ __launch_bounds__(1024) void k_scan_top(
    int* __restrict__ blocksum, int nb, int* __restrict__ offsets, int N)
{
    __shared__ int sums[1024];
    int t = threadIdx.x;
    int v = (t < nb) ? blocksum[t] : 0;
    sums[t] = v;
    __syncthreads();
    #pragma unroll
    for (int d = 1; d < 1024; d <<= 1) {
        int u = (t >= d) ? sums[t - d] : 0;
        __syncthreads();
        sums[t] += u;
        __syncthreads();
    }
    if (t < nb) blocksum[t] = sums[t] - v;
    if (t == nb - 1) offsets[N] = sums[t];
}

// ---------------------------------------------------------------------------
// K3c: add block base; write offsets + cursor.
// ---------------------------------------------------------------------------
__global__ __launch_bounds__(1024) void k_scan_add(
    const int* __restrict__ local, const int* __restrict__ blocksum,
    int* __restrict__ offsets, int* __restrict__ cursor, int N)
{
    int base = blockIdx.x * 4096 + threadIdx.x * 4;
    int bs = blocksum[blockIdx.x];
    if (base + 3 < N) {
        int4 o = *(const int4*)&local[base];
        o.x += bs; o.y += bs; o.z += bs; o.w += bs;
        *(int4*)&offsets[base] = o;
        *(int4*)&cursor[base]  = o;
    } else {
        for (int j = 0; j < 4; ++j)
            if (base + j < N) {
                int o = local[base + j] + bs;
                offsets[base + j] = o;
                cursor[base + j]  = o;
            }
    }
}

// ---------------------------------------------------------------------------
// K4: fused edge stream: a_edge dot + CSR scatter, ONE int4 (16B) per edge:
// {src, bf16(ae0,ae1), bf16(ae2,ae3), 0}. No node-array gathers here (R4
// lesson: they thrash L2 against the 205MB stream).
// ---------------------------------------------------------------------------
__global__ __launch_bounds__(256) void k_scatter(
    const float* __restrict__ edge_attr, const int* __restrict__ ei,
    const float* __restrict__ v_edge, int* __restrict__ cursor,
    int4* __restrict__ csr, int E)
{
    __shared__ float vl[HC];
    int t = threadIdx.x;
    if (t < HC) vl[t] = v_edge[t];
    __syncthreads();

    int e = blockIdx.x * 256 + t;
    if (e >= E) return;

    const float4* ea4 = (const float4*)edge_attr + (size_t)e * 8;
    float ae[4] = {0.f, 0.f, 0.f, 0.f};
    #pragma unroll
    for (int j = 0; j < 8; ++j) {
        float4 v = ea4[j];
        #pragma unroll
        for (int h = 0; h < 4; ++h) {
            const float* vh = &vl[h * 32 + j * 4];
            ae[h] += v.x * vh[0] + v.y * vh[1] + v.z * vh[2] + v.w * vh[3];
        }
    }
    int src = ei[e], dst = ei[E + e];
    int pos = atomicAdd(&cursor[dst], 1);
    int4 pk;
    pk.x = src;
    pk.y = (int)pack_bf16(ae[0], ae[1]);
    pk.z = (int)pack_bf16(ae[2], ae[3]);
    pk.w = 0;
    csr[pos] = pk;
}

// ---------------------------------------------------------------------------
// K5: fused pull: logit finish (a_src gather + a_dst + exp) + softmax denom +
// weighted sum + bias + LayerNorm + LeakyReLU. 32 lanes/node, lane owns 4
// channels. 4-edge groups with 1-ahead prefetch.
// ---------------------------------------------------------------------------
__global__ __launch_bounds__(256) void k_agg(
    const int* __restrict__ offsets, const int4* __restrict__ csr,
    const float* __restrict__ a_src, const float* __restrict__ a_dst,
    const unsigned* __restrict__ xb, const float* __restrict__ bias,
    const float* __restrict__ gamma, const float* __restrict__ beta,
    float* __restrict__ out, int N)
{
    int t = threadIdx.x;
    int node = blockIdx.x * 8 + (t >> 5);
    int lane = t & 31;
    if (node >= N) return;
    int st = offsets[node], en = offsets[node + 1];
    int hsel = lane >> 3;
    float adst = a_dst[node * 4 + hsel];
    const uint2* x2 = (const uint2*)xb;
    float4 acc = {0.f, 0.f, 0.f, 0.f};
    float denom = 0.f;

    int s_c[4]; float ae_c[4], as_c[4];

    if (st < en) {
        #pragma unroll
        for (int j = 0; j < 4; ++j) {
            bool v = (st + j) < en;
            int a = v ? (st + j) : 0;
            int4 pk = csr[a];
            s_c[j] = pk.x;
            unsigned w = (hsel & 2) ? (unsigned)pk.z : (unsigned)pk.y;
            float e = __uint_as_float((hsel & 1) ? (w & 0xffff0000u) : (w << 16));
            ae_c[j] = v ? e : -1e30f;
        }
        #pragma unroll
        for (int j = 0; j < 4; ++j) as_c[j] = a_src[s_c[j] * 4 + hsel];

        for (int p = st; p < en; p += 4) {
            int pn = p + 4;
            int s_n[4]; float ae_n[4], as_n[4];
            #pragma unroll
            for (int j = 0; j < 4; ++j) {
                bool v = (pn + j) < en;
                int a = v ? (pn + j) : 0;
                int4 pk = csr[a];
                s_n[j] = pk.x;
                unsigned w = (hsel & 2) ? (unsigned)pk.z : (unsigned)pk.y;
                float e = __uint_as_float((hsel & 1) ? (w & 0xffff0000u) : (w << 16));
                ae_n[j] = v ? e : -1e30f;
            }
            #pragma unroll
            for (int j = 0; j < 4; ++j) as_n[j] = a_src[s_n[j] * 4 + hsel];

            #pragma unroll
            for (int j = 0; j < 4; ++j) {
                float al = as_c[j] + adst + ae_c[j];
                al = (al < 0.f) ? 0.2f * al : al;
                float ex = __expf(al);
                denom += ex;
                uint2 xv = x2[(size_t)s_c[j] * 32 + lane];
                float x0 = __uint_as_float(xv.x << 16);
                float x1 = __uint_as_float(xv.x & 0xffff0000u);
                float xA = __uint_as_float(xv.y << 16);
                float x3 = __uint_as_float(xv.y & 0xffff0000u);
                acc.x += ex * x0; acc.y += ex * x1;
                acc.z += ex * xA; acc.w += ex * x3;
            }
            #pragma unroll
            for (int j = 0; j < 4; ++j) {
                s_c[j] = s_n[j]; ae_c[j] = ae_n[j]; as_c[j] = as_n[j];
            }
        }
    }
    float inv = 1.f / (denom + 1e-16f);
    float4 o = {acc.x * inv, acc.y * inv, acc.z * inv, acc.w * inv};

    // fused +bias, LayerNorm(128), LeakyReLU(0.01); reduce across 32 lanes
    int c = lane * 4;
    float4 b4 = *(const float4*)&bias[c];
    o.x += b4.x; o.y += b4.y; o.z += b4.z; o.w += b4.w;
    float s = o.x + o.y + o.z + o.w;
    #pragma unroll
    for (int m = 1; m < 32; m <<= 1) s += __shfl_xor(s, m, 32);
    float mu = s * (1.0f / 128.0f);
    float d0 = o.x - mu, d1 = o.y - mu, d2 = o.z - mu, d3 = o.w - mu;
    float q = d0 * d0 + d1 * d1 + d2 * d2 + d3 * d3;
    #pragma unroll
    for (int m = 1; m < 32; m <<= 1) q += __shfl_xor(q, m, 32);
    float rstd = rsqrtf(q * (1.0f / 128.0f) + 1e-5f);
    float4 g4 = *(const float4*)&gamma[c];
    float4 be4 = *(const float4*)&beta[c];
    float y0 = d0 * rstd * g4.x + be4.x;
    float y1 = d1 * rstd * g4.y + be4.y;
    float y2 = d2 * rstd * g4.z + be4.z;
    float y3 = d3 * rstd * g4.w + be4.w;
    y0 = (y0 < 0.f) ? 0.01f * y0 : y0;
    y1 = (y1 < 0.f) ? 0.01f * y1 : y1;
    y2 = (y2 < 0.f) ? 0.01f * y2 : y2;
    y3 = (y3 < 0.f) ? 0.01f * y3 : y3;
    float4 r = {y0, y1, y2, y3};
    ((float4*)out)[(size_t)node * 32 + lane] = r;
}

// ---------------------------------------------------------------------------
extern "C" void kernel_launch(void* const* d_in, const int* in_sizes, int n_in,
                              void* d_out, int out_size, void* d_ws, size_t ws_size,
                              hipStream_t stream) {
    const float* point_attr = (const float*)d_in[0];
    const int*   edge_index = (const int*)d_in[1];
    const float* edge_attr  = (const float*)d_in[2];
    const float* W          = (const float*)d_in[3];
    const float* att_src    = (const float*)d_in[4];
    const float* att_dst    = (const float*)d_in[5];
    const float* W_edge     = (const float*)d_in[6];
    const float* att_edge   = (const float*)d_in[7];
    const float* bias       = (const float*)d_in[8];
    const float* ln_gamma   = (const float*)d_in[9];
    const float* ln_beta    = (const float*)d_in[10];

    int N = in_sizes[0] / IN_DIM;
    int E = in_sizes[2] / EDGE_DIM;
    float* out = (float*)d_out;

    char* ws = (char*)d_ws;
    size_t off = 0;
    auto alloc = [&](size_t bytes) {
        void* p = ws + off;
        off += (bytes + 255) & ~(size_t)255;
        return p;
    };
    unsigned* xb     = (unsigned*)alloc((size_t)N * 128 * 2);   // bf16 x
    float* a_src     = (float*)alloc((size_t)N * 4 * 4);
    float* a_dst     = (float*)alloc((size_t)N * 4 * 4);
    int*   degree    = (int*)alloc((size_t)N * 4);
    int*   offsets   = (int*)alloc((size_t)(N + 1) * 4);
    int*   cursor    = (int*)alloc((size_t)N * 4);
    int*   scanloc   = (int*)alloc((size_t)N * 4);
    int*   blocksum  = (int*)alloc(1024 * 4);
    float* v_edge    = (float*)alloc(128 * 4);
    int4*  csr       = (int4*)alloc((size_t)E * 16);

    hipMemsetAsync(degree, 0, (size_t)N * 4, stream);

    int nb = (N + 4095) / 4096;

    k_vedge<<<1, 128, 0, stream>>>(W_edge, att_edge, v_edge);
    k_gemm_x<<<(N + 127) / 128, 256, 0, stream>>>(point_attr, W, att_src, att_dst,
                                                  xb, a_src, a_dst, N);
    k_degree<<<(E + 255) / 256, 256, 0, stream>>>(edge_index, degree, E);
    k_scan_blk<<<nb, 1024, 0, stream>>>(degree, scanloc, blocksum, N);
    k_scan_top<<<1, 1024, 0, stream>>>(blocksum, nb, offsets, N);
    k_scan_add<<<nb, 1024, 0, stream>>>(scanloc, blocksum, offsets, cursor, N);
    k_scatter<<<(E + 255) / 256, 256, 0, stream>>>(edge_attr, edge_index, v_edge,
                                                   cursor, csr, E);
    k_agg<<<(N + 7) / 8, 256, 0, stream>>>(offsets, csr, a_src, a_dst, xb,
                                           bias, ln_gamma, ln_beta, out, N);
}